// Round 5
// baseline (289.212 us; speedup 1.0000x reference)
//
#include <hip/hip_runtime.h>
#include <cstddef>

#define B_ROWS 8192
#define DIM    1024
#define NSESS  32
#define MT     256       // rows per M-tile (TPE*MT=512 >= validated 384 max)
#define NTILE  256       // cols per N-tile
#define BK     32        // k-elems per phase = 1 MFMA k-step
#define KITERS (DIM / BK)   // 32
#define TPE    2         // m-tiles per expert
#define LROW   40        // shorts per LDS row: 32 bf16 + 8 pad = 80 B
#define TSZ    (MT * LROW)
#define NXCD   8
#define EPX    (NSESS / NXCD)        // experts per XCD = 4
#define BPE    (TPE * (DIM / NTILE)) // blocks per expert = 8

typedef __attribute__((ext_vector_type(8))) short short8;
typedef __attribute__((ext_vector_type(4))) float floatx4;
typedef __attribute__((ext_vector_type(4))) int intx4;
typedef __attribute__((ext_vector_type(2))) unsigned int uintx2;

// RNE fp32->bf16 for two values, packed into one dword via v_perm_b32.
__device__ __forceinline__ unsigned pack_bf16_2(float fa, float fb) {
  unsigned a = __builtin_bit_cast(unsigned, fa);
  unsigned b = __builtin_bit_cast(unsigned, fb);
  a += 0x7fffu + ((a >> 16) & 1u);
  b += 0x7fffu + ((b >> 16) & 1u);
  return __builtin_amdgcn_perm(b, a, 0x07060302u); // low = bf16(fa), high = bf16(fb)
}

// Round-10 (post-mortem r9: touching d_ws triggers a 512MiB re-poison fill
// (~80us) EVERY iteration + 40us of convert traffic per call -> bf16 pre-pass
// net zero. Workspace is off-limits; the r1 note was right). The r8 service
// model (time = vector-load bytes / ~4.9TB/s, occupancy-insensitive) survived
// two perturbations; this round cuts BYTES with geometry, not dtype:
//  - 256x256 tile, 512 thr / 8 waves (2Mx4N, wave tile 128x64, acc[8][4]=128r)
//  - x re-read 8x -> 4x (128MB), W re-read ~2.4x -> ~1.5x (192MB): demand
//    670 -> ~360MB, no pre-pass, no workspace
//  - BK=32: per-thread in-flight 4+4 float4 (32 regs); est peak ~200 regs ->
//    __launch_bounds__(512,2) (256-reg cap), no spill (canary: WRITE~39MB)
//  - grid 256 blocks = 1/CU; XCD-clustered (256%8==0, bijective)
//  - keep: r6 single-buffer loop, k0-B prefetch before scan, bf16 LDS +pad,
//    ranked compaction (psum/row_ids now 512/256 wide)
__global__ __launch_bounds__(512, 2) void gemm_kernel(
    const float* __restrict__ x, const float* __restrict__ W,
    const float* __restrict__ bias, const int* __restrict__ sidx,
    float* __restrict__ out)
{
  __shared__ __align__(16) short As[TSZ], Bs[TSZ];
  __shared__ int row_ids[MT];
  __shared__ int psum[512];

  // ---- XCD-clustered decode ----
  const int hw    = blockIdx.x;          // 0..255, assumed XCD = hw % 8
  const int xcd   = hw & (NXCD - 1);
  const int r     = hw >> 3;             // 0..31: within-XCD sequence
  const int s     = xcd * EPX + (r / BPE);   // expert, clustered per XCD
  const int rr    = r % BPE;             // 0..7
  const int ntile = rr >> 1;             // 0..3 (W slice shared by 2 mtiles)
  const int mtile = rr & 1;
  const int tid   = threadIdx.x;

  const int lane = tid & 63;
  const int wv   = tid >> 6;            // wave id 0..7
  const int wm   = wv >> 2;             // 0..1 : 128-row half
  const int wn   = wv & 3;              // 0..3 : 64-col quarter
  const int fr   = lane & 15;           // fragment row within 16
  const int kg   = lane >> 4;           // fragment k-group (k = kg*8 + j)

  // ---- staging: row chunk = 128B = 8 lanes x 16B; rows srow + j*64 ----
  const int srow = tid >> 3;            // 0..63
  const int sch  = tid & 7;             // 16-B chunk within 128-B k-row

  // B byte-offsets + k0 B-loads issued before the sidx scan.
  unsigned boff[4];
  floatx4 wr[4];
  {
    const unsigned wbyte =
        (unsigned)(((size_t)s * DIM * DIM + (size_t)(ntile * NTILE) * DIM) * 4u);
#pragma unroll
    for (int j = 0; j < 4; ++j) {
      boff[j] = wbyte + (unsigned)(((srow + j * 64) * DIM + sch * 4) * 4);
      wr[j] = *(const floatx4*)((const char*)W + boff[j]);
    }
  }

  // ---- ranked compaction: rows with sidx==s, ranks [mtile*256, +256) ----
  const intx4* sv = (const intx4*)(sidx + tid * 16);
  int c = 0;
#pragma unroll
  for (int j = 0; j < 4; ++j) {
    const intx4 v = sv[j];
#pragma unroll
    for (int e = 0; e < 4; ++e) c += (v[e] == s);
  }
  psum[tid] = c;
  __syncthreads();
#pragma unroll
  for (int d = 1; d < 512; d <<= 1) {
    const int mine = psum[tid];
    const int add  = (tid >= d) ? psum[tid - d] : 0;
    __syncthreads();
    psum[tid] = mine + add;
    __syncthreads();
  }
  const int total = psum[511];
  const int nrows = (total - mtile * MT) < 0 ? 0
                  : ((total - mtile * MT) > MT ? MT : (total - mtile * MT));
  if (nrows == 0) return;               // uniform across block
  const int base_rank = psum[tid] - c;

  if (tid < MT) row_ids[tid] = -1;
  __syncthreads();
  {
    int r2 = base_rank;
    const int lo = mtile * MT, hi = lo + MT;
#pragma unroll
    for (int j = 0; j < 4; ++j) {
      const intx4 v = sv[j];
#pragma unroll
      for (int e = 0; e < 4; ++e) {
        if (v[e] == s) {
          if (r2 >= lo && r2 < hi) row_ids[r2 - lo] = tid * 16 + 4 * j + e;
          ++r2;
        }
      }
    }
  }
  __syncthreads();

  unsigned aoff[4];
  floatx4 xr[4];
#pragma unroll
  for (int j = 0; j < 4; ++j) {
    int ar = row_ids[srow + j * 64];
    if (ar < 0) ar = 0;                 // dummy; epilogue masks rows >= nrows
    aoff[j] = (unsigned)((ar * DIM + sch * 4) * 4);
    xr[j] = *(const floatx4*)((const char*)x + aoff[j]);   // k0 A-loads
  }

  floatx4 acc[8][4] = {};

#define LOADREGS(KB)                                                           \
  {                                                                            \
    _Pragma("unroll")                                                          \
    for (int j = 0; j < 4; ++j) {                                              \
      xr[j] = *(const floatx4*)((const char*)x + aoff[j] + (KB) * (BK * 4));   \
      wr[j] = *(const floatx4*)((const char*)W + boff[j] + (KB) * (BK * 4));   \
    }                                                                          \
  }

#define CVTWRITE()                                                             \
  {                                                                            \
    _Pragma("unroll")                                                          \
    for (int j = 0; j < 4; ++j) {                                              \
      const int off = (srow + j * 64) * LROW + sch * 4;                        \
      uintx2 ua = { pack_bf16_2(xr[j][0], xr[j][1]),                           \
                    pack_bf16_2(xr[j][2], xr[j][3]) };                         \
      uintx2 ub = { pack_bf16_2(wr[j][0], wr[j][1]),                           \
                    pack_bf16_2(wr[j][2], wr[j][3]) };                         \
      *(uintx2*)&As[off] = ua;                                                 \
      *(uintx2*)&Bs[off] = ub;                                                 \
    }                                                                          \
  }

#define COMPUTE()                                                              \
  {                                                                            \
    short8 fb[4];                                                              \
    _Pragma("unroll")                                                          \
    for (int i = 0; i < 4; ++i)                                                \
      fb[i] = *(const short8*)&Bs[(wn * 64 + i * 16 + fr) * LROW + kg * 8];    \
    _Pragma("unroll")                                                          \
    for (int mi = 0; mi < 8; ++mi) {                                           \
      const short8 fa = *(const short8*)&As[(wm * 128 + mi * 16 + fr) * LROW + kg * 8]; \
      _Pragma("unroll")                                                        \
      for (int ni = 0; ni < 4; ++ni)                                           \
        acc[mi][ni] = __builtin_amdgcn_mfma_f32_16x16x32_bf16(                 \
            fa, fb[ni], acc[mi][ni], 0, 0, 0);                                 \
    }                                                                          \
  }

  // prologue: k0 already in regs -> stage into LDS
  CVTWRITE();
  __syncthreads();

  for (int kb = 0; kb < KITERS; ++kb) {
    if (kb + 1 < KITERS) LOADREGS(kb + 1);   // in flight across compute+barrier
    COMPUTE();
    if (kb + 1 < KITERS) {
      __syncthreads();                       // all waves done reading LDS
      CVTWRITE();                            // vmcnt wait lands here
      __syncthreads();                       // writes visible
    }
  }

#undef LOADREGS
#undef CVTWRITE
#undef COMPUTE

  // epilogue: D row = kg*4 + reg, D col = lane&15
  const int col0 = ntile * NTILE + wn * 64;
#pragma unroll
  for (int ni = 0; ni < 4; ++ni) {
    const int n = col0 + ni * 16 + fr;
    const float bv = bias[s * DIM + n];
#pragma unroll
    for (int mi = 0; mi < 8; ++mi) {
      const int mbase = wm * 128 + mi * 16 + kg * 4;
#pragma unroll
      for (int rr2 = 0; rr2 < 4; ++rr2) {
        const int ml = mbase + rr2;
        if (ml < nrows) {
          const int orow = row_ids[ml];
          out[(size_t)orow * DIM + n] = acc[mi][ni][rr2] + bv;
        }
      }
    }
  }
}

extern "C" void kernel_launch(void* const* d_in, const int* in_sizes, int n_in,
                              void* d_out, int out_size, void* d_ws, size_t ws_size,
                              hipStream_t stream) {
  const float* x    = (const float*)d_in[0];
  const float* W    = (const float*)d_in[1];
  const float* b    = (const float*)d_in[2];
  const int*   sidx = (const int*)d_in[3];
  float* out = (float*)d_out;
  (void)d_ws; (void)ws_size;  // OFF-LIMITS: any ws touch => 512MiB re-poison
                              // fill (~80us) per iteration (r9 post-mortem)

  hipLaunchKernelGGL(gemm_kernel, dim3(NSESS * TPE * (DIM / NTILE)), dim3(512),
                     0, stream, x, W, b, sidx, out);
}